// Round 1
// baseline (76554.962 us; speedup 1.0000x reference)
//
#include <hip/hip_runtime.h>
#include <math.h>

// LSTM seq2seq: 2-layer encoder (T=256) + 2-layer autoregressive decoder (FUT=96)
// B=256, H=512, fp32 everywhere. Round 1: correct fp32 baseline.
// Structure: one kernel per LSTM cell step (graph-captured), column-partitioned
// weights so each block always touches the same weight columns (L2-resident).

namespace {
constexpr int Hh   = 512;
constexpr int G4   = 4 * Hh;      // 2048 gate columns
constexpr int Bb   = 256;
constexpr int Tt   = 256;
constexpr int INF_ = 32;
constexpr int OUTF_= 8;
constexpr int FUT_ = 96;

__device__ __forceinline__ float sigm(float x) { return 1.f / (1.f + __expf(-x)); }
__device__ __forceinline__ float tanh_fast(float x) {
  return 2.f / (1.f + __expf(-2.f * x)) - 1.f;
}
} // namespace

// One LSTM cell step: gates = x@Wih^T + h@Whh^T + (bih+bhh); c,h update fused.
// grid = 256 blocks: cg = blockIdx&15 (32 h-cols), bg = blockIdx>>4 (16 batch rows)
// block = 256 threads: ct = t&31 (owns 4 consecutive gate cols), rt = t>>5 (rows rt, rt+8)
template<int KIN>
__global__ __launch_bounds__(256, 1) void lstm_cell_k(
    const float* __restrict__ x, int ldx,
    const float* __restrict__ h_in,
    float* __restrict__ c_io,
    float* __restrict__ h_out,
    const float* __restrict__ Wih,
    const float* __restrict__ Whh,
    const float* __restrict__ bih,
    const float* __restrict__ bhh)
{
  constexpr int CHX = (KIN < 32) ? KIN : 32;
  const int cg   = blockIdx.x & 15;
  const int bg   = blockIdx.x >> 4;
  const int t    = threadIdx.x;
  const int ct   = t & 31;
  const int rt   = t >> 5;
  const int l0   = ct * 4;                          // local gate-col base (0..124)
  const int n0   = (l0 >> 5) * Hh + cg * 32 + (l0 & 31); // global gate col (4 consecutive, same gate)
  const int row0 = bg * 16;

  __shared__ float As[16][32];    // [m][k] staging of x / h tile
  __shared__ float Gs[16][128];   // gate exchange

  float acc[2][4] = {{0.f,0.f,0.f,0.f},{0.f,0.f,0.f,0.f}};

  // ---- phase X: x @ Wih^T, K = KIN ----
  for (int k0 = 0; k0 < KIN; k0 += CHX) {
    __syncthreads();
    for (int i = t; i < 16 * CHX; i += 256) {
      int m = i / CHX, k = i - m * CHX;
      As[m][k] = x[(row0 + m) * ldx + k0 + k];
    }
    __syncthreads();
#pragma unroll
    for (int kk = 0; kk < CHX; kk += 4) {
      float4 a0 = *(const float4*)&As[rt][kk];
      float4 a1 = *(const float4*)&As[rt + 8][kk];
#pragma unroll
      for (int r = 0; r < 4; ++r) {
        float4 w = *(const float4*)&Wih[(n0 + r) * KIN + k0 + kk];
        acc[0][r] += a0.x * w.x + a0.y * w.y + a0.z * w.z + a0.w * w.w;
        acc[1][r] += a1.x * w.x + a1.y * w.y + a1.z * w.z + a1.w * w.w;
      }
    }
  }

  // ---- phase H: h @ Whh^T, K = 512 ----
  for (int k0 = 0; k0 < Hh; k0 += 32) {
    __syncthreads();
    {
      int m = t >> 5;      // 0..7
      int k = t & 31;
      As[m][k]     = h_in[(row0 + m) * Hh + k0 + k];
      As[m + 8][k] = h_in[(row0 + m + 8) * Hh + k0 + k];
    }
    __syncthreads();
#pragma unroll
    for (int kk = 0; kk < 32; kk += 4) {
      float4 a0 = *(const float4*)&As[rt][kk];
      float4 a1 = *(const float4*)&As[rt + 8][kk];
#pragma unroll
      for (int r = 0; r < 4; ++r) {
        float4 w = *(const float4*)&Whh[(n0 + r) * Hh + k0 + kk];
        acc[0][r] += a0.x * w.x + a0.y * w.y + a0.z * w.z + a0.w * w.w;
        acc[1][r] += a1.x * w.x + a1.y * w.y + a1.z * w.z + a1.w * w.w;
      }
    }
  }

  // ---- bias + gate exchange ----
#pragma unroll
  for (int r = 0; r < 4; ++r) {
    float bb = bih[n0 + r] + bhh[n0 + r];
    acc[0][r] += bb;
    acc[1][r] += bb;
  }
  __syncthreads();
  *(float4*)&Gs[rt][l0]     = make_float4(acc[0][0], acc[0][1], acc[0][2], acc[0][3]);
  *(float4*)&Gs[rt + 8][l0] = make_float4(acc[1][0], acc[1][1], acc[1][2], acc[1][3]);
  __syncthreads();

  // ---- cell update: 16 rows x 32 h-cols, 2 elements per thread ----
  for (int idx = t; idx < 512; idx += 256) {
    int m = idx >> 5, j = idx & 31;
    float iv = Gs[m][j];
    float fv = Gs[m][32 + j];
    float gv = Gs[m][64 + j];
    float ov = Gs[m][96 + j];
    int row = row0 + m, col = cg * 32 + j;
    float c  = c_io[row * Hh + col];
    float cn = sigm(fv) * c + sigm(iv) * tanh_fast(gv);
    float hn = sigm(ov) * tanh_fast(cn);
    c_io[row * Hh + col]  = cn;
    h_out[row * Hh + col] = hn;
  }
}

// out[:, s, :] = h1 @ fc_W^T + fc_b ; grid 8 blocks x 256 threads
__global__ __launch_bounds__(256, 1) void fc_k(
    const float* __restrict__ h1, float* __restrict__ out,
    const float* __restrict__ fcW, const float* __restrict__ fcb, int s)
{
  int t = threadIdx.x;
  int f = t & 7;
  int m = t >> 3;                       // 0..31
  int row = blockIdx.x * 32 + m;
  float dot = 0.f;
#pragma unroll 8
  for (int k = 0; k < Hh; k += 4) {
    float4 hv = *(const float4*)&h1[row * Hh + k];
    float4 wv = *(const float4*)&fcW[f * Hh + k];
    dot += hv.x * wv.x + hv.y * wv.y + hv.z * wv.z + hv.w * wv.w;
  }
  out[row * (FUT_ * OUTF_) + s * OUTF_ + f] = dot + fcb[f];
}

extern "C" void kernel_launch(void* const* d_in, const int* in_sizes, int n_in,
                              void* d_out, int out_size, void* d_ws, size_t ws_size,
                              hipStream_t stream) {
  const float* in_seq = (const float*)d_in[0];
  const float* eW0i = (const float*)d_in[1];
  const float* eW0h = (const float*)d_in[2];
  const float* eb0i = (const float*)d_in[3];
  const float* eb0h = (const float*)d_in[4];
  const float* eW1i = (const float*)d_in[5];
  const float* eW1h = (const float*)d_in[6];
  const float* eb1i = (const float*)d_in[7];
  const float* eb1h = (const float*)d_in[8];
  const float* dW0i = (const float*)d_in[9];
  const float* dW0h = (const float*)d_in[10];
  const float* db0i = (const float*)d_in[11];
  const float* db0h = (const float*)d_in[12];
  const float* dW1i = (const float*)d_in[13];
  const float* dW1h = (const float*)d_in[14];
  const float* db1i = (const float*)d_in[15];
  const float* db1h = (const float*)d_in[16];
  const float* fcW  = (const float*)d_in[17];
  const float* fcb  = (const float*)d_in[18];
  float* out = (float*)d_out;

  float* ws = (float*)d_ws;
  const size_t S = (size_t)Bb * Hh;     // 131072 floats per state buffer
  float* h0[2] = {ws, ws + S};
  float* c0    = ws + 2 * S;
  float* h1[2] = {ws + 3 * S, ws + 4 * S};
  float* c1    = ws + 5 * S;

  // zero-init h0, c0, h1, c1 (harness re-poisons ws with 0xAA before each call)
  hipMemsetAsync(d_ws, 0, 6 * S * sizeof(float), stream);

  int p0 = 0, p1 = 0;
  // ---- encoder ----
  for (int ts = 0; ts < Tt; ++ts) {
    lstm_cell_k<INF_><<<256, 256, 0, stream>>>(
        in_seq + ts * INF_, Tt * INF_,
        h0[p0], c0, h0[p0 ^ 1], eW0i, eW0h, eb0i, eb0h);
    p0 ^= 1;
    lstm_cell_k<Hh><<<256, 256, 0, stream>>>(
        h0[p0], Hh,
        h1[p1], c1, h1[p1 ^ 1], eW1i, eW1h, eb1i, eb1h);
    p1 ^= 1;
  }
  // ---- decoder (states continue from encoder) ----
  for (int s = 0; s < FUT_; ++s) {
    const float* xp = (s == 0) ? (in_seq + (Tt - 1) * INF_)
                               : (out + (size_t)(s - 1) * OUTF_);
    int ldx = (s == 0) ? (Tt * INF_) : (FUT_ * OUTF_);
    lstm_cell_k<OUTF_><<<256, 256, 0, stream>>>(
        xp, ldx, h0[p0], c0, h0[p0 ^ 1], dW0i, dW0h, db0i, db0h);
    p0 ^= 1;
    lstm_cell_k<Hh><<<256, 256, 0, stream>>>(
        h0[p0], Hh, h1[p1], c1, h1[p1 ^ 1], dW1i, dW1h, db1i, db1h);
    p1 ^= 1;
    fc_k<<<8, 256, 0, stream>>>(h1[p1], out, fcW, fcb, s);
  }
}

// Round 2
// 51698.273 us; speedup vs baseline: 1.4808x; 1.4808x over previous
//
#include <hip/hip_runtime.h>
#include <hip/hip_cooperative_groups.h>

namespace cg = cooperative_groups;

typedef short bf16x8 __attribute__((ext_vector_type(8)));
typedef float f32x4 __attribute__((ext_vector_type(4)));

namespace {
constexpr int Hh    = 512;
constexpr int Bb    = 256;
constexpr int Tt    = 256;
constexpr int INF_  = 32;
constexpr int OUTF_ = 8;
constexpr int FUT_  = 96;
constexpr int NGATE = 2048;

constexpr size_t WPLANE = (size_t)NGATE * Hh;    // 1,048,576 ushorts per weight plane
constexpr size_t HPLANE = (size_t)Bb * Hh;       // 131,072 ushorts per h plane
constexpr size_t OFF_H    = 12 * WPLANE;         // h planes after 12 weight planes
constexpr size_t OFF_BIAS = OFF_H + 8 * HPLANE;  // fp32 bias area (ushort offset)

__device__ __forceinline__ unsigned short f2bf(float f) {
  unsigned u = __float_as_uint(f);
  u += 0x7fffu + ((u >> 16) & 1u);
  return (unsigned short)(u >> 16);
}
__device__ __forceinline__ float bf2f(unsigned short h) {
  return __uint_as_float(((unsigned)h) << 16);
}
__device__ __forceinline__ float sigm(float x) { return 1.f / (1.f + __expf(-x)); }
__device__ __forceinline__ float tanh_fast(float x) {
  return 2.f / (1.f + __expf(-2.f * x)) - 1.f;
}
} // namespace

// ---- prep: split 6 recurrent/ih weight matrices into bf16 hi/lo planes,
// zero h state planes, precompute per-layer bias sums. Re-runs every call.
__global__ void prep_k(const float* __restrict__ eWhh0, const float* __restrict__ eWih1,
                       const float* __restrict__ eWhh1, const float* __restrict__ dWhh0,
                       const float* __restrict__ dWih1, const float* __restrict__ dWhh1,
                       const float* __restrict__ eb0i, const float* __restrict__ eb0h,
                       const float* __restrict__ eb1i, const float* __restrict__ eb1h,
                       const float* __restrict__ db0i, const float* __restrict__ db0h,
                       const float* __restrict__ db1i, const float* __restrict__ db1h,
                       unsigned short* __restrict__ ws)
{
  size_t i0 = (size_t)blockIdx.x * blockDim.x + threadIdx.x;
  size_t stride = (size_t)gridDim.x * blockDim.x;
  const float* srcs[6] = {eWhh0, eWih1, eWhh1, dWhh0, dWih1, dWhh1};
  for (size_t i = i0; i < 6 * WPLANE; i += stride) {
    int m = (int)(i / WPLANE);
    size_t e = i - (size_t)m * WPLANE;
    float w = srcs[m][e];
    unsigned short hi = f2bf(w);
    float lo = w - bf2f(hi);
    ws[(size_t)(2 * m) * WPLANE + e]     = hi;
    ws[(size_t)(2 * m + 1) * WPLANE + e] = f2bf(lo);
  }
  for (size_t i = i0; i < 8 * HPLANE; i += stride) ws[OFF_H + i] = 0;
  float* bias = (float*)(ws + OFF_BIAS);
  for (size_t i = i0; i < 4 * 2048; i += stride) {
    int which = (int)(i >> 11);
    int n = (int)(i & 2047);
    float v = (which == 0) ? eb0i[n] + eb0h[n]
            : (which == 1) ? eb1i[n] + eb1h[n]
            : (which == 2) ? db0i[n] + db0h[n]
            :                db1i[n] + db1h[n];
    bias[i] = v;
  }
}

// ---- persistent cooperative kernel: whole seq2seq in one launch.
// 256 blocks x 512 threads. Blocks 0..127: layer-0 role; 128..255: layer-1 + FC.
// Per role: 4 M-groups (64 batch rows) x 32 N-groups (16 h-cols x 4 gates = 64 gate cols).
// Wave tile 32(M)x16(N); MFMA 16x16x32 bf16, split hi/lo (3 products).
__global__ __launch_bounds__(512, 2)
void lstm_persist_k(const float* __restrict__ in_seq,
                    const float* __restrict__ eWih0,
                    const float* __restrict__ dWih0,
                    const float* __restrict__ fcW,
                    const float* __restrict__ fcb,
                    unsigned short* __restrict__ ws,
                    float* __restrict__ out)
{
  cg::grid_group grid = cg::this_grid();
  const int tid  = threadIdx.x;
  const int bid  = blockIdx.x;
  const int role = bid >> 7;        // 0 = L0, 1 = L1(+FC)
  const int lb   = bid & 127;
  const int mg   = lb >> 5;         // 0..3  -> rows mg*64..+63
  const int ng   = lb & 31;         // 0..31 -> h-cols ng*16..+15
  const int l    = tid & 63;
  const int wv   = tid >> 6;        // 0..7
  const int wm   = wv >> 2;         // 0..1  -> 32-row half
  const int wn   = wv & 3;          // 0..3  == gate index (16 cols each)
  const int l15  = l & 15;
  const int lk8  = (l >> 4) * 8;    // k offset of this lane's 8 elems
  const int rowb = mg * 64 + wm * 32;
  const int ncol = wn * 512 + ng * 16 + l15;   // global gate column (B/C frag col)

  unsigned short* h0hi[2] = { ws + OFF_H + 0 * HPLANE, ws + OFF_H + 1 * HPLANE };
  unsigned short* h0lo[2] = { ws + OFF_H + 2 * HPLANE, ws + OFF_H + 3 * HPLANE };
  unsigned short* h1hi[2] = { ws + OFF_H + 4 * HPLANE, ws + OFF_H + 5 * HPLANE };
  unsigned short* h1lo[2] = { ws + OFF_H + 6 * HPLANE, ws + OFF_H + 7 * HPLANE };
  const float* bias = (const float*)(ws + OFF_BIAS);

  const unsigned short* eWhh0h = ws + 0 * WPLANE; const unsigned short* eWhh0l = ws + 1 * WPLANE;
  const unsigned short* eWih1h = ws + 2 * WPLANE; const unsigned short* eWih1l = ws + 3 * WPLANE;
  const unsigned short* eWhh1h = ws + 4 * WPLANE; const unsigned short* eWhh1l = ws + 5 * WPLANE;
  const unsigned short* dWhh0h = ws + 6 * WPLANE; const unsigned short* dWhh0l = ws + 7 * WPLANE;
  const unsigned short* dWih1h = ws + 8 * WPLANE; const unsigned short* dWih1l = ws + 9 * WPLANE;
  const unsigned short* dWhh1h = ws + 10 * WPLANE; const unsigned short* dWhh1l = ws + 11 * WPLANE;

  __shared__ float gs[64][64];      // gate pre-activations (block tile)
  __shared__ float hshare[64][16];  // h slice for FC partial

  // persistent cell state: 2 elements per thread, fixed (row, col) for 704 steps
  float creg[2] = {0.f, 0.f};
  const int ci  = tid * 2;
  const int cr  = ci >> 4;          // 0..63 local row
  const int cj0 = ci & 15;          // even local h-col

  auto gemmK = [&](f32x4* acc, const unsigned short* Ahi, const unsigned short* Alo,
                   const unsigned short* Whi, const unsigned short* Wlo) {
    const unsigned short* wh  = Whi + (size_t)ncol * Hh + lk8;
    const unsigned short* wl  = Wlo + (size_t)ncol * Hh + lk8;
    const unsigned short* ahp = Ahi + (size_t)(rowb + l15) * Hh + lk8;
    const unsigned short* alp = Alo + (size_t)(rowb + l15) * Hh + lk8;
#pragma unroll 4
    for (int k0 = 0; k0 < Hh; k0 += 32) {
      bf16x8 bh  = *(const bf16x8*)(wh + k0);
      bf16x8 bl  = *(const bf16x8*)(wl + k0);
      bf16x8 ah0 = *(const bf16x8*)(ahp + k0);
      bf16x8 ah1 = *(const bf16x8*)(ahp + 16 * Hh + k0);
      bf16x8 al0 = *(const bf16x8*)(alp + k0);
      bf16x8 al1 = *(const bf16x8*)(alp + 16 * Hh + k0);
      acc[0] = __builtin_amdgcn_mfma_f32_16x16x32_bf16(ah0, bh, acc[0], 0, 0, 0);
      acc[1] = __builtin_amdgcn_mfma_f32_16x16x32_bf16(ah1, bh, acc[1], 0, 0, 0);
      acc[0] = __builtin_amdgcn_mfma_f32_16x16x32_bf16(al0, bh, acc[0], 0, 0, 0);
      acc[1] = __builtin_amdgcn_mfma_f32_16x16x32_bf16(al1, bh, acc[1], 0, 0, 0);
      acc[0] = __builtin_amdgcn_mfma_f32_16x16x32_bf16(ah0, bl, acc[0], 0, 0, 0);
      acc[1] = __builtin_amdgcn_mfma_f32_16x16x32_bf16(ah1, bl, acc[1], 0, 0, 0);
    }
  };

  auto cellStore = [&](f32x4* acc) {   // acc -> LDS in C-frag layout
#pragma unroll
    for (int mf = 0; mf < 2; ++mf)
#pragma unroll
      for (int rg = 0; rg < 4; ++rg)
        gs[wm * 32 + mf * 16 + (l >> 4) * 4 + rg][wn * 16 + l15] = acc[mf][rg];
  };

  auto cellUpdate = [&](int bsel, unsigned short* Hhi, unsigned short* Hlo, bool fc) {
    const float* bb = bias + bsel * 2048 + ng * 16;
#pragma unroll
    for (int e = 0; e < 2; ++e) {
      int jj = cj0 + e;
      float iv = gs[cr][jj]      + bb[jj];
      float fv = gs[cr][16 + jj] + bb[512 + jj];
      float gv = gs[cr][32 + jj] + bb[1024 + jj];
      float ov = gs[cr][48 + jj] + bb[1536 + jj];
      float cn = sigm(fv) * creg[e] + sigm(iv) * tanh_fast(gv);
      float hn = sigm(ov) * tanh_fast(cn);
      creg[e] = cn;
      unsigned short hi = f2bf(hn);
      float lo = hn - bf2f(hi);
      size_t off = (size_t)(mg * 64 + cr) * Hh + ng * 16 + jj;
      Hhi[off] = hi;
      Hlo[off] = f2bf(lo);
      if (fc) hshare[cr][jj] = hn;
    }
  };

  auto fcReduce = [&](int s) {
    int r = tid >> 3;
    int f = tid & 7;
    const float* wf = fcW + (size_t)f * Hh + ng * 16;
    float sacc = 0.f;
#pragma unroll
    for (int jj = 0; jj < 16; ++jj) sacc += hshare[r][jj] * wf[jj];
    atomicAdd(&out[(size_t)(mg * 64 + r) * (FUT_ * OUTF_) + s * OUTF_ + f], sacc);
  };

  auto xPartEnc = [&](f32x4* acc, int t) {   // exact fp32 x @ Wih0^T, K=32
    float4 wvv[8];
    const float* wr = eWih0 + (size_t)ncol * INF_;
#pragma unroll
    for (int q = 0; q < 8; ++q) wvv[q] = *(const float4*)(wr + 4 * q);
#pragma unroll
    for (int mf = 0; mf < 2; ++mf)
#pragma unroll
      for (int rg = 0; rg < 4; ++rg) {
        int r = rowb + mf * 16 + (l >> 4) * 4 + rg;
        const float* xr = in_seq + (size_t)r * (Tt * INF_) + (size_t)t * INF_;
        float s = 0.f;
#pragma unroll
        for (int q = 0; q < 8; ++q) {
          float4 xv = *(const float4*)(xr + 4 * q);
          s += xv.x * wvv[q].x + xv.y * wvv[q].y + xv.z * wvv[q].z + xv.w * wvv[q].w;
        }
        acc[mf][rg] += s;
      }
  };

  auto xPartDec = [&](f32x4* acc, int s) {   // exact fp32 x @ dWih0^T, K=8
    float w8[8];
    const float* wr = dWih0 + (size_t)ncol * OUTF_;
#pragma unroll
    for (int q = 0; q < 8; ++q) w8[q] = wr[q];
#pragma unroll
    for (int mf = 0; mf < 2; ++mf)
#pragma unroll
      for (int rg = 0; rg < 4; ++rg) {
        int r = rowb + mf * 16 + (l >> 4) * 4 + rg;
        const float* xr = (s == 0) ? (in_seq + (size_t)r * (Tt * INF_) + (size_t)(Tt - 1) * INF_)
                                   : (out + (size_t)r * (FUT_ * OUTF_) + (size_t)(s - 1) * OUTF_);
        float sv = 0.f;
#pragma unroll
        for (int q = 0; q < 8; ++q) sv += xr[q] * w8[q];
        acc[mf][rg] += sv;
      }
  };

  // ---------------- encoder: ticks t=0..256, L0(t) || L1(t-1) ----------------
  for (int t = 0; t <= Tt; ++t) {
    if (role == 0) {
      if (t < Tt) {
        f32x4 acc[2] = {{0.f, 0.f, 0.f, 0.f}, {0.f, 0.f, 0.f, 0.f}};
        xPartEnc(acc, t);
        gemmK(acc, h0hi[(t + 1) & 1], h0lo[(t + 1) & 1], eWhh0h, eWhh0l);
        cellStore(acc);
        __syncthreads();
        cellUpdate(0, h0hi[t & 1], h0lo[t & 1], false);
      }
    } else {
      if (t >= 1) {
        int st = t - 1;
        f32x4 acc[2] = {{0.f, 0.f, 0.f, 0.f}, {0.f, 0.f, 0.f, 0.f}};
        gemmK(acc, h0hi[st & 1], h0lo[st & 1], eWih1h, eWih1l);
        gemmK(acc, h1hi[(st + 1) & 1], h1lo[(st + 1) & 1], eWhh1h, eWhh1l);
        cellStore(acc);
        __syncthreads();
        cellUpdate(1, h1hi[st & 1], h1lo[st & 1], false);
      }
    }
    __threadfence();
    grid.sync();
  }

  // ---------------- decoder: 2 ticks per step s ----------------
  for (int s = 0; s < FUT_; ++s) {
    int pr = (s & 1) ^ 1;   // state buffer before step s
    int pw = s & 1;         // state buffer written by step s
    // tick A: L0(s); L1 blocks init out slice s with fc bias
    if (role == 0) {
      f32x4 acc[2] = {{0.f, 0.f, 0.f, 0.f}, {0.f, 0.f, 0.f, 0.f}};
      xPartDec(acc, s);
      gemmK(acc, h0hi[pr], h0lo[pr], dWhh0h, dWhh0l);
      cellStore(acc);
      __syncthreads();
      cellUpdate(2, h0hi[pw], h0lo[pw], false);
    } else {
      if (tid < 16) {
        int idx = lb * 16 + tid;
        out[(size_t)(idx >> 3) * (FUT_ * OUTF_) + s * OUTF_ + (idx & 7)] = fcb[idx & 7];
      }
    }
    __threadfence();
    grid.sync();
    // tick B: L1(s) + FC partial
    if (role == 1) {
      f32x4 acc[2] = {{0.f, 0.f, 0.f, 0.f}, {0.f, 0.f, 0.f, 0.f}};
      gemmK(acc, h0hi[pw], h0lo[pw], dWih1h, dWih1l);
      gemmK(acc, h1hi[pr], h1lo[pr], dWhh1h, dWhh1l);
      cellStore(acc);
      __syncthreads();
      cellUpdate(3, h1hi[pw], h1lo[pw], true);
      __syncthreads();
      fcReduce(s);
    }
    __threadfence();
    grid.sync();
  }
}

extern "C" void kernel_launch(void* const* d_in, const int* in_sizes, int n_in,
                              void* d_out, int out_size, void* d_ws, size_t ws_size,
                              hipStream_t stream) {
  const float* in_seq = (const float*)d_in[0];
  const float* eWih0  = (const float*)d_in[1];
  const float* eWhh0  = (const float*)d_in[2];
  const float* eb0i   = (const float*)d_in[3];
  const float* eb0h   = (const float*)d_in[4];
  const float* eWih1  = (const float*)d_in[5];
  const float* eWhh1  = (const float*)d_in[6];
  const float* eb1i   = (const float*)d_in[7];
  const float* eb1h   = (const float*)d_in[8];
  const float* dWih0  = (const float*)d_in[9];
  const float* dWhh0  = (const float*)d_in[10];
  const float* db0i   = (const float*)d_in[11];
  const float* db0h   = (const float*)d_in[12];
  const float* dWih1  = (const float*)d_in[13];
  const float* dWhh1  = (const float*)d_in[14];
  const float* db1i   = (const float*)d_in[15];
  const float* db1h   = (const float*)d_in[16];
  const float* fcW    = (const float*)d_in[17];
  const float* fcb    = (const float*)d_in[18];
  float* outp = (float*)d_out;
  unsigned short* wsp = (unsigned short*)d_ws;

  prep_k<<<1024, 256, 0, stream>>>(eWhh0, eWih1, eWhh1, dWhh0, dWih1, dWhh1,
                                   eb0i, eb0h, eb1i, eb1h, db0i, db0h, db1i, db1h,
                                   wsp);

  void* kargs[] = {(void*)&in_seq, (void*)&eWih0, (void*)&dWih0, (void*)&fcW,
                   (void*)&fcb, (void*)&wsp, (void*)&outp};
  hipLaunchCooperativeKernel((const void*)lstm_persist_k, dim3(256), dim3(512),
                             kargs, 0, stream);
}

// Round 5
// 8943.686 us; speedup vs baseline: 8.5597x; 5.7804x over previous
//
#include <hip/hip_runtime.h>

typedef short bf16x8 __attribute__((ext_vector_type(8)));
typedef float f32x4 __attribute__((ext_vector_type(4)));
typedef unsigned long long u64;

namespace {
constexpr int Hh = 512, Tt = 256, OUTF_ = 8, FUT_ = 96;
constexpr int NBLK = 256;

constexpr size_t WPLANE = 2048ull * 512;        // ushorts per weight plane (2MB)
constexpr size_t HPLANE = 256ull * 512;         // ushorts per h plane
constexpr size_t OFF_H    = 12 * WPLANE;
constexpr size_t OFF_BIAS = OFF_H + 8 * HPLANE;       // fp32 bias area (ushort idx)
constexpr size_t OFF_BAR  = OFF_BIAS + 16384;         // barrier cells after 8192 fp32 bias

__device__ __forceinline__ unsigned short f2bf(float f) {
  unsigned u = __float_as_uint(f);
  u += 0x7fffu + ((u >> 16) & 1u);
  return (unsigned short)(u >> 16);
}
__device__ __forceinline__ float bf2f(unsigned short h) {
  return __uint_as_float(((unsigned)h) << 16);
}
__device__ __forceinline__ float sigm(float x) { return 1.f / (1.f + __expf(-x)); }
__device__ __forceinline__ float tanh_fast(float x) {
  return 2.f / (1.f + __expf(-2.f * x)) - 1.f;
}

// coherent-point accesses (sc0 sc1): bypass the non-coherent per-XCD L2s,
// no cache-maintenance instructions ever issued.
__device__ __forceinline__ u64 sysload_u64(const void* p) {
  return __hip_atomic_load((const u64*)p, __ATOMIC_RELAXED, __HIP_MEMORY_SCOPE_SYSTEM);
}
__device__ __forceinline__ void sysstore_u32(void* p, unsigned v) {
  __hip_atomic_store((unsigned*)p, v, __ATOMIC_RELAXED, __HIP_MEMORY_SCOPE_SYSTEM);
}
__device__ __forceinline__ void sysstore_f32(void* p, float v) {
  __hip_atomic_store((float*)p, v, __ATOMIC_RELAXED, __HIP_MEMORY_SCOPE_SYSTEM);
}
} // namespace

// ---- prep: split 6 K=512 matrices into bf16 hi/lo planes, zero h planes,
// bias sums, zero barrier cells. Re-runs every call (ws re-poisoned).
__global__ void prep_k(const float* __restrict__ eWhh0, const float* __restrict__ eWih1,
                       const float* __restrict__ eWhh1, const float* __restrict__ dWhh0,
                       const float* __restrict__ dWih1, const float* __restrict__ dWhh1,
                       const float* __restrict__ eb0i, const float* __restrict__ eb0h,
                       const float* __restrict__ eb1i, const float* __restrict__ eb1h,
                       const float* __restrict__ db0i, const float* __restrict__ db0h,
                       const float* __restrict__ db1i, const float* __restrict__ db1h,
                       unsigned short* __restrict__ ws)
{
  size_t i0 = (size_t)blockIdx.x * blockDim.x + threadIdx.x;
  size_t stride = (size_t)gridDim.x * blockDim.x;
  const float* srcs[6] = {eWhh0, eWih1, eWhh1, dWhh0, dWih1, dWhh1};
  for (size_t i = i0; i < 6 * WPLANE; i += stride) {
    int m = (int)(i / WPLANE);
    size_t e = i - (size_t)m * WPLANE;
    float w = srcs[m][e];
    unsigned short hi = f2bf(w);
    float lo = w - bf2f(hi);
    ws[(size_t)(2 * m) * WPLANE + e]     = hi;
    ws[(size_t)(2 * m + 1) * WPLANE + e] = f2bf(lo);
  }
  for (size_t i = i0; i < 8 * HPLANE; i += stride) ws[OFF_H + i] = 0;
  float* bias = (float*)(ws + OFF_BIAS);
  for (size_t i = i0; i < 4 * 2048; i += stride) {
    int which = (int)(i >> 11);
    int n = (int)(i & 2047);
    float v = (which == 0) ? eb0i[n] + eb0h[n]
            : (which == 1) ? eb1i[n] + eb1h[n]
            : (which == 2) ? db0i[n] + db0h[n]
            :                db1i[n] + db1h[n];
    bias[i] = v;
  }
  unsigned* barp = (unsigned*)(ws + OFF_BAR);
  for (size_t i = i0; i < 64; i += stride) barp[i] = 0;
}

// ---- persistent kernel: 256 blocks x 512 threads, fence-free grid barrier.
// role = bid>>7 (0: L0, 1: L1+FC). Per role 128 blocks: mg=lb>>4 (32 batch
// rows), ng=lb&15 (32 h-cols -> 128 gate cols). 8 waves: wave wv -> gate
// g=wv>>1, col-half jh=wv&1 (16 cols). MFMA 16x16x32 bf16, hi/lo split.
// LDS A-stage in K-halves of 256 to stay under the 64KB static LDS limit.
__global__ __launch_bounds__(512, 2)
void lstm_persist_k(const float* __restrict__ in_seq,
                    const float* __restrict__ eWih0,
                    const float* __restrict__ dWih0,
                    const float* __restrict__ fcW,
                    const float* __restrict__ fcb,
                    unsigned short* __restrict__ ws,
                    float* __restrict__ out)
{
  const int tid  = threadIdx.x;
  const int bid  = blockIdx.x;
  const int role = bid >> 7;
  const int lb   = bid & 127;
  const int mg   = lb >> 4;          // 0..7  rows mg*32..+31
  const int ng   = lb & 15;          // 0..15 h-cols ng*32..+31
  const int l    = tid & 63;
  const int wv   = tid >> 6;         // 0..7
  const int l15  = l & 15;
  const int lk8  = (l >> 4) * 8;
  const int g    = wv >> 1;          // gate index
  const int jh   = wv & 1;
  const int ncol = g * 512 + ng * 32 + jh * 16 + l15;  // global gate column
  const int row0 = mg * 32;

  unsigned short* h0hi[2] = { ws + OFF_H + 0 * HPLANE, ws + OFF_H + 1 * HPLANE };
  unsigned short* h0lo[2] = { ws + OFF_H + 2 * HPLANE, ws + OFF_H + 3 * HPLANE };
  unsigned short* h1hi[2] = { ws + OFF_H + 4 * HPLANE, ws + OFF_H + 5 * HPLANE };
  unsigned short* h1lo[2] = { ws + OFF_H + 6 * HPLANE, ws + OFF_H + 7 * HPLANE };
  const float* bias = (const float*)(ws + OFF_BIAS);
  unsigned* bcnt = (unsigned*)(ws + OFF_BAR);
  unsigned* brel = (unsigned*)(ws + OFF_BAR) + 32;

  const unsigned short* eWhh0h = ws + 0 * WPLANE;  const unsigned short* eWhh0l = ws + 1 * WPLANE;
  const unsigned short* eWih1h = ws + 2 * WPLANE;  const unsigned short* eWih1l = ws + 3 * WPLANE;
  const unsigned short* eWhh1h = ws + 4 * WPLANE;  const unsigned short* eWhh1l = ws + 5 * WPLANE;
  const unsigned short* dWhh0h = ws + 6 * WPLANE;  const unsigned short* dWhh0l = ws + 7 * WPLANE;
  const unsigned short* dWih1h = ws + 8 * WPLANE;  const unsigned short* dWih1l = ws + 9 * WPLANE;
  const unsigned short* dWhh1h = ws + 10 * WPLANE; const unsigned short* dWhh1l = ws + 11 * WPLANE;

  __shared__ unsigned short Ast[2 * 32 * 256];   // 32KB: one K-half, hi+lo, swizzled
  __shared__ float gs[32][132];                  // 16.9KB gate exchange
  __shared__ float hshare[32][32];               // 4KB h slice for FC
  __shared__ float xs[32][8];                    // 1KB decoder x stage

  float creg[2] = {0.f, 0.f};
  const int cr  = tid >> 4;          // 0..31 local row (cell update)
  const int cj0 = (tid & 15) * 2;    // even local h-col

  int bar_tick = 0;
  auto gbar = [&]() {
    asm volatile("s_waitcnt vmcnt(0)" ::: "memory");  // drain sys-stores/atomics
    __syncthreads();
    ++bar_tick;
    if (tid == 0) {
      unsigned old = __hip_atomic_fetch_add(bcnt, 1u, __ATOMIC_RELAXED,
                                            __HIP_MEMORY_SCOPE_AGENT);
      if (old + 1u == (unsigned)NBLK * (unsigned)bar_tick) {
        __hip_atomic_store(brel, (unsigned)bar_tick, __ATOMIC_RELAXED,
                           __HIP_MEMORY_SCOPE_AGENT);
      } else {
        int guard = 0;
        while (__hip_atomic_load(brel, __ATOMIC_RELAXED, __HIP_MEMORY_SCOPE_AGENT) <
                   (unsigned)bar_tick &&
               ++guard < (1 << 19))
          __builtin_amdgcn_s_sleep(2);
      }
    }
    __syncthreads();
  };

  // stage rows row0..row0+31, k in [kh*256, kh*256+256), hi+lo planes -> 32KB LDS
  auto stageA = [&](const unsigned short* Ahi, const unsigned short* Alo, int kh) {
    u64 v[8];
    int bofs[8];
#pragma unroll
    for (int q = 0; q < 8; ++q) {
      int ch = tid + q * 512;            // 0..4095 chunks of 8B
      int plane = ch >> 11;
      int rem = ch & 2047;
      int row = rem >> 6;                // 0..31
      int kc = (rem & 63) * 4;           // ushort col within 256-col half
      const unsigned short* src =
          (plane ? Alo : Ahi) + (size_t)(row0 + row) * 512 + kh * 256 + kc;
      v[q] = sysload_u64((const void*)src);
      bofs[q] = (plane * 16384 + row * 512 + (kc << 1)) ^ ((row & 7) << 4);
    }
#pragma unroll
    for (int q = 0; q < 8; ++q)
      *(u64*)((char*)Ast + bofs[q]) = v[q];
  };

  auto ldsA = [&](int plane, int mb, int k0) -> bf16x8 {
    int row = mb + l15;
    int b = (plane * 16384 + row * 512 + ((k0 + lk8) << 1)) ^ ((row & 7) << 4);
    return *(const bf16x8*)((const char*)Ast + b);
  };

  // full K=512 GEMM in two staged halves; hi/lo split (6 MFMA / 32-k step)
  auto gemmStaged = [&](f32x4* acc, const unsigned short* Ahi, const unsigned short* Alo,
                        const unsigned short* Whi, const unsigned short* Wlo) {
#pragma unroll
    for (int kh = 0; kh < 2; ++kh) {
      __syncthreads();                   // prior LDS consumers done
      stageA(Ahi, Alo, kh);
      __syncthreads();
      const unsigned short* wh = Whi + (size_t)ncol * 512 + kh * 256 + lk8;
      const unsigned short* wl = Wlo + (size_t)ncol * 512 + kh * 256 + lk8;
#pragma unroll
      for (int k0 = 0; k0 < 256; k0 += 32) {
        bf16x8 bh  = *(const bf16x8*)(wh + k0);
        bf16x8 bl  = *(const bf16x8*)(wl + k0);
        bf16x8 ah0 = ldsA(0, 0, k0);
        bf16x8 ah1 = ldsA(0, 16, k0);
        bf16x8 al0 = ldsA(1, 0, k0);
        bf16x8 al1 = ldsA(1, 16, k0);
        acc[0] = __builtin_amdgcn_mfma_f32_16x16x32_bf16(ah0, bh, acc[0], 0, 0, 0);
        acc[1] = __builtin_amdgcn_mfma_f32_16x16x32_bf16(ah1, bh, acc[1], 0, 0, 0);
        acc[0] = __builtin_amdgcn_mfma_f32_16x16x32_bf16(al0, bh, acc[0], 0, 0, 0);
        acc[1] = __builtin_amdgcn_mfma_f32_16x16x32_bf16(al1, bh, acc[1], 0, 0, 0);
        acc[0] = __builtin_amdgcn_mfma_f32_16x16x32_bf16(ah0, bl, acc[0], 0, 0, 0);
        acc[1] = __builtin_amdgcn_mfma_f32_16x16x32_bf16(ah1, bl, acc[1], 0, 0, 0);
      }
    }
  };

  auto cellStore = [&](f32x4* acc) {
#pragma unroll
    for (int mf = 0; mf < 2; ++mf)
#pragma unroll
      for (int rg = 0; rg < 4; ++rg)
        gs[mf * 16 + (l >> 4) * 4 + rg][wv * 16 + l15] = acc[mf][rg];
  };

  auto cellUpdate = [&](int bsel, unsigned short* Hhi, unsigned short* Hlo, bool fc) {
    const float* bb = bias + bsel * 2048 + ng * 32;
    float hn2[2];
#pragma unroll
    for (int e = 0; e < 2; ++e) {
      int j = cj0 + e;
      float iv = gs[cr][j]      + bb[j];
      float fv = gs[cr][32 + j] + bb[512 + j];
      float gv = gs[cr][64 + j] + bb[1024 + j];
      float ov = gs[cr][96 + j] + bb[1536 + j];
      float cn = sigm(fv) * creg[e] + sigm(iv) * tanh_fast(gv);
      float hn = sigm(ov) * tanh_fast(cn);
      creg[e] = cn;
      hn2[e] = hn;
      if (fc) hshare[cr][j] = hn;
    }
    unsigned short hi0 = f2bf(hn2[0]), hi1 = f2bf(hn2[1]);
    unsigned short lo0 = f2bf(hn2[0] - bf2f(hi0)), lo1 = f2bf(hn2[1] - bf2f(hi1));
    size_t uidx = ((size_t)(row0 + cr) * 512 + ng * 32 + cj0) >> 1;
    sysstore_u32((unsigned*)Hhi + uidx, (unsigned)hi0 | ((unsigned)hi1 << 16));
    sysstore_u32((unsigned*)Hlo + uidx, (unsigned)lo0 | ((unsigned)lo1 << 16));
  };

  auto xPartEnc = [&](f32x4* acc, int t) {     // exact fp32 x@Wih0^T, K=32
    float4 wvv[8];
    const float* wr = eWih0 + (size_t)ncol * 32;
#pragma unroll
    for (int q = 0; q < 8; ++q) wvv[q] = *(const float4*)(wr + 4 * q);
#pragma unroll
    for (int mf = 0; mf < 2; ++mf)
#pragma unroll
      for (int rg = 0; rg < 4; ++rg) {
        int rl = mf * 16 + (l >> 4) * 4 + rg;
        const float* xr = in_seq + (size_t)(row0 + rl) * 8192 + (size_t)t * 32;
        float s = 0.f;
#pragma unroll
        for (int q = 0; q < 8; ++q) {
          float4 xv = *(const float4*)(xr + 4 * q);
          s += xv.x * wvv[q].x + xv.y * wvv[q].y + xv.z * wvv[q].z + xv.w * wvv[q].w;
        }
        acc[mf][rg] += s;
      }
  };

  auto xDecStage = [&](int s) {                // stage decoder x (8 fp32/row)
    if (tid < 128) {
      int r = tid >> 2, p2 = (tid & 3) * 2;
      int rowg = row0 + r;
      const void* src = (s == 0)
          ? (const void*)(in_seq + (size_t)rowg * 8192 + 8160 + p2)
          : (const void*)(out + (size_t)rowg * 768 + (size_t)(s - 1) * 8 + p2);
      u64 v = sysload_u64(src);
      *(u64*)&xs[r][p2] = v;
    }
  };

  auto xPartDec = [&](f32x4* acc) {            // exact fp32 x@dWih0^T, K=8
    float w8[8];
    const float* wr = dWih0 + (size_t)ncol * 8;
#pragma unroll
    for (int q = 0; q < 8; ++q) w8[q] = wr[q];
#pragma unroll
    for (int mf = 0; mf < 2; ++mf)
#pragma unroll
      for (int rg = 0; rg < 4; ++rg) {
        int rl = mf * 16 + (l >> 4) * 4 + rg;
        float sv = 0.f;
#pragma unroll
        for (int q = 0; q < 8; ++q) sv += xs[rl][q] * w8[q];
        acc[mf][rg] += sv;
      }
  };

  // ---------------- encoder: ticks t=0..256, L0(t) || L1(t-1) ----------------
  for (int t = 0; t <= Tt; ++t) {
    if (role == 0) {
      if (t < Tt) {
        f32x4 acc[2] = {{0.f,0.f,0.f,0.f},{0.f,0.f,0.f,0.f}};
        xPartEnc(acc, t);
        gemmStaged(acc, h0hi[(t + 1) & 1], h0lo[(t + 1) & 1], eWhh0h, eWhh0l);
        cellStore(acc);
        __syncthreads();
        cellUpdate(0, h0hi[t & 1], h0lo[t & 1], false);
      }
    } else if (t >= 1) {
      int st = t - 1;
      f32x4 acc[2] = {{0.f,0.f,0.f,0.f},{0.f,0.f,0.f,0.f}};
      gemmStaged(acc, h0hi[st & 1], h0lo[st & 1], eWih1h, eWih1l);
      gemmStaged(acc, h1hi[(st + 1) & 1], h1lo[(st + 1) & 1], eWhh1h, eWhh1l);
      cellStore(acc);
      __syncthreads();
      cellUpdate(1, h1hi[st & 1], h1lo[st & 1], false);
    }
    gbar();
  }

  // ---------------- decoder: 2 ticks per step ----------------
  for (int s = 0; s < FUT_; ++s) {
    int pr = (s & 1) ^ 1, pw = s & 1;
    if (role == 0) {
      f32x4 acc[2] = {{0.f,0.f,0.f,0.f},{0.f,0.f,0.f,0.f}};
      xDecStage(s);
      gemmStaged(acc, h0hi[pr], h0lo[pr], dWhh0h, dWhh0l);
      xPartDec(acc);                      // xs visible (syncs inside gemmStaged)
      cellStore(acc);
      __syncthreads();
      cellUpdate(2, h0hi[pw], h0lo[pw], false);
    } else {
      if (tid < 16)
        sysstore_f32(&out[(size_t)(lb * 2 + (tid >> 3)) * 768 + (size_t)s * 8 + (tid & 7)],
                     fcb[tid & 7]);
    }
    gbar();
    if (role == 1) {
      f32x4 acc[2] = {{0.f,0.f,0.f,0.f},{0.f,0.f,0.f,0.f}};
      gemmStaged(acc, h0hi[pw], h0lo[pw], dWih1h, dWih1l);
      gemmStaged(acc, h1hi[pr], h1lo[pr], dWhh1h, dWhh1l);
      cellStore(acc);
      __syncthreads();
      cellUpdate(3, h1hi[pw], h1lo[pw], true);
      __syncthreads();
      if (tid < 256) {
        int r = tid >> 3, f = tid & 7;
        const float* wf = fcW + (size_t)f * 512 + ng * 32;
        float sacc = 0.f;
#pragma unroll
        for (int jj = 0; jj < 32; ++jj) sacc += hshare[r][jj] * wf[jj];
        atomicAdd(&out[(size_t)(row0 + r) * 768 + (size_t)s * 8 + f], sacc);
      }
    }
    gbar();
  }
}

extern "C" void kernel_launch(void* const* d_in, const int* in_sizes, int n_in,
                              void* d_out, int out_size, void* d_ws, size_t ws_size,
                              hipStream_t stream) {
  const float* in_seq = (const float*)d_in[0];
  const float* eWih0  = (const float*)d_in[1];
  const float* eWhh0  = (const float*)d_in[2];
  const float* eb0i   = (const float*)d_in[3];
  const float* eb0h   = (const float*)d_in[4];
  const float* eWih1  = (const float*)d_in[5];
  const float* eWhh1  = (const float*)d_in[6];
  const float* eb1i   = (const float*)d_in[7];
  const float* eb1h   = (const float*)d_in[8];
  const float* dWih0  = (const float*)d_in[9];
  const float* dWhh0  = (const float*)d_in[10];
  const float* db0i   = (const float*)d_in[11];
  const float* db0h   = (const float*)d_in[12];
  const float* dWih1  = (const float*)d_in[13];
  const float* dWhh1  = (const float*)d_in[14];
  const float* db1i   = (const float*)d_in[15];
  const float* db1h   = (const float*)d_in[16];
  const float* fcW    = (const float*)d_in[17];
  const float* fcb    = (const float*)d_in[18];
  float* outp = (float*)d_out;
  unsigned short* wsp = (unsigned short*)d_ws;

  prep_k<<<1024, 256, 0, stream>>>(eWhh0, eWih1, eWhh1, dWhh0, dWih1, dWhh1,
                                   eb0i, eb0h, eb1i, eb1h, db0i, db0h, db1i, db1h,
                                   wsp);

  void* kargs[] = {(void*)&in_seq, (void*)&eWih0, (void*)&dWih0, (void*)&fcW,
                   (void*)&fcb, (void*)&wsp, (void*)&outp};
  hipLaunchCooperativeKernel((const void*)lstm_persist_k, dim3(NBLK), dim3(512),
                             kargs, 0, stream);
}